// Round 1
// baseline (184.534 us; speedup 1.0000x reference)
//
#include <hip/hip_runtime.h>
#include <hip/hip_bf16.h>

// Problem constants
#define BATCH 8
#define CDIM 256     // QDIM == KDIM
#define SEQ 1024     // 32*32
#define EMB 512
#define NHEAD 8
#define HDIM 64

typedef __bf16 bf16x8 __attribute__((ext_vector_type(8)));
typedef float f32x4 __attribute__((ext_vector_type(4)));

static __device__ __forceinline__ unsigned short f2b(float f) {
    __hip_bfloat16 h = __float2bfloat16(f);
    return __builtin_bit_cast(unsigned short, h);
}

static __device__ __forceinline__ f32x4 mfma16(bf16x8 a, bf16x8 b, f32x4 c) {
    return __builtin_amdgcn_mfma_f32_16x16x32_bf16(a, b, c, 0, 0, 0);
}

// ---------------------------------------------------------------------------
// Kernel 1: (B, C, S) f32 -> (B, S, C) bf16 transpose+convert, 64x64 LDS tiles
// grid (S/64=16, C/64=4, 2*B=16), block 256
// ---------------------------------------------------------------------------
__global__ __launch_bounds__(256) void transpose_cvt(
    const float* __restrict__ query, const float* __restrict__ key_,
    unsigned short* __restrict__ Xq, unsigned short* __restrict__ Xk)
{
    __shared__ alignas(16) unsigned short sT[64 * 66];  // pad 66: conflict-free col reads
    int tid = threadIdx.x;
    int s0 = blockIdx.x * 64, c0 = blockIdx.y * 64;
    int z = blockIdx.z;
    int which = z >> 3, b = z & 7;
    const float* src = which ? key_ : query;
    unsigned short* dst = which ? Xk : Xq;

#pragma unroll
    for (int p = 0; p < 4; ++p) {
        int c = (tid >> 4) + p * 16;
        int sch = tid & 15;
        float4 v = *(const float4*)&src[((size_t)b * CDIM + c0 + c) * SEQ + s0 + sch * 4];
        sT[c * 66 + sch * 4 + 0] = f2b(v.x);
        sT[c * 66 + sch * 4 + 1] = f2b(v.y);
        sT[c * 66 + sch * 4 + 2] = f2b(v.z);
        sT[c * 66 + sch * 4 + 3] = f2b(v.w);
    }
    __syncthreads();
#pragma unroll
    for (int p = 0; p < 4; ++p) {
        int s = (tid >> 4) + p * 16;
        int cch = tid & 15;
        unsigned short e0 = sT[(cch * 4 + 0) * 66 + s];
        unsigned short e1 = sT[(cch * 4 + 1) * 66 + s];
        unsigned short e2 = sT[(cch * 4 + 2) * 66 + s];
        unsigned short e3 = sT[(cch * 4 + 3) * 66 + s];
        uint2 pk;
        pk.x = (unsigned)e0 | ((unsigned)e1 << 16);
        pk.y = (unsigned)e2 | ((unsigned)e3 << 16);
        *(uint2*)&dst[((size_t)b * SEQ + s0 + s) * CDIM + c0 + cch * 4] = pk;
    }
}

// ---------------------------------------------------------------------------
// Kernel 2: projection GEMM  C[b,s,e] = X[b,s,:] . W[e,:] + bias[e]
// X bf16 (B,S,C), W f32 (E,C) converted inline. BM=128 BN=64 BK=64, 4 waves.
// Writes: proj0 -> Q (B,H,S,D) *0.125 ; proj1 -> K (B,H,S,D) ; proj2 -> V^T (B,H,D,S)
// grid (E/64=8, S/128=8, 3*B=24), block 256
// ---------------------------------------------------------------------------
__global__ __launch_bounds__(256) void proj_kernel(
    const unsigned short* __restrict__ Xq, const unsigned short* __restrict__ Xk,
    const float* __restrict__ Wq, const float* __restrict__ bq,
    const float* __restrict__ Wk, const float* __restrict__ bk,
    const float* __restrict__ Wv, const float* __restrict__ bv,
    unsigned short* __restrict__ Qb, unsigned short* __restrict__ Kb,
    unsigned short* __restrict__ Vt)
{
    __shared__ alignas(16) unsigned short sA[128 * 72];  // [s][c], +8 pad
    __shared__ alignas(16) unsigned short sB[64 * 72];   // [e][c], +8 pad
    int tid = threadIdx.x;
    int z = blockIdx.z;
    int proj = z >> 3, b = z & 7;
    int n0 = blockIdx.x * 64, s0 = blockIdx.y * 128;
    const unsigned short* X = (proj == 0) ? Xq : Xk;
    const float* W = (proj == 0) ? Wq : (proj == 1 ? Wk : Wv);
    const float* bias = (proj == 0) ? bq : (proj == 1 ? bk : bv);

    int lane = tid & 63, w = tid >> 6;
    int l16 = lane & 15, lhi = lane >> 4;
    int wr = w >> 1, wc = w & 1;  // wave tile: 64 rows x 32 cols

    f32x4 zero = {0.f, 0.f, 0.f, 0.f};
    f32x4 acc[4][2];
#pragma unroll
    for (int i = 0; i < 4; ++i)
#pragma unroll
        for (int j = 0; j < 2; ++j) acc[i][j] = zero;

    for (int kt = 0; kt < 4; ++kt) {
        int c0 = kt * 64;
        // stage A: 128x64 bf16, b128 copies
#pragma unroll
        for (int p = 0; p < 4; ++p) {
            int row = (tid >> 3) + p * 32, ch = tid & 7;
            *(int4*)&sA[row * 72 + ch * 8] =
                *(const int4*)&X[((size_t)b * SEQ + s0 + row) * CDIM + c0 + ch * 8];
        }
        // stage B: 64x64, f32 -> bf16 inline
#pragma unroll
        for (int p = 0; p < 4; ++p) {
            int e = (tid >> 4) + p * 16, ch = tid & 15;
            float4 v = *(const float4*)&W[((size_t)(n0 + e)) * CDIM + c0 + ch * 4];
            uint2 pk;
            pk.x = (unsigned)f2b(v.x) | ((unsigned)f2b(v.y) << 16);
            pk.y = (unsigned)f2b(v.z) | ((unsigned)f2b(v.w) << 16);
            *(uint2*)&sB[e * 72 + ch * 4] = pk;
        }
        __syncthreads();
#pragma unroll
        for (int kk = 0; kk < 2; ++kk) {
            bf16x8 af[4], bfg[2];
#pragma unroll
            for (int mf = 0; mf < 4; ++mf)
                af[mf] = *(const bf16x8*)&sA[(wr * 64 + mf * 16 + l16) * 72 + kk * 32 + lhi * 8];
#pragma unroll
            for (int nf = 0; nf < 2; ++nf)
                bfg[nf] = *(const bf16x8*)&sB[(wc * 32 + nf * 16 + l16) * 72 + kk * 32 + lhi * 8];
#pragma unroll
            for (int mf = 0; mf < 4; ++mf)
#pragma unroll
                for (int nf = 0; nf < 2; ++nf)
                    acc[mf][nf] = mfma16(af[mf], bfg[nf], acc[mf][nf]);
        }
        __syncthreads();
    }

    float scale = (proj == 0) ? 0.125f : 1.0f;  // fold 1/sqrt(64) into Q (exact pow2)
#pragma unroll
    for (int mf = 0; mf < 4; ++mf) {
#pragma unroll
        for (int nf = 0; nf < 2; ++nf) {
            int e = n0 + wc * 32 + nf * 16 + l16;
            float bval = bias[e];
            int hh = e >> 6, dd = e & 63;
#pragma unroll
            for (int r = 0; r < 4; ++r) {
                int s = s0 + wr * 64 + mf * 16 + lhi * 4 + r;
                float val = (acc[mf][nf][r] + bval) * scale;
                unsigned short ov = f2b(val);
                if (proj == 2)
                    Vt[((size_t)(b * NHEAD + hh) * HDIM + dd) * SEQ + s] = ov;
                else if (proj == 1)
                    Kb[((size_t)(b * NHEAD + hh) * SEQ + s) * HDIM + dd] = ov;
                else
                    Qb[((size_t)(b * NHEAD + hh) * SEQ + s) * HDIM + dd] = ov;
            }
        }
    }
}

// ---------------------------------------------------------------------------
// Kernel 3: causal flash attention, one WG per (qblock=64 rows, b*h).
// 4 waves x 16 q-rows each. KV tile = 64. Q,K (B,H,S,D) bf16; V^T (B,H,D,S) bf16.
// out f32 (B, E, S): out[b, h*64+d, s] = O[s][d]
// grid (S/64=16, B*H=64), block 256
// ---------------------------------------------------------------------------
__global__ __launch_bounds__(256) void attn_kernel(
    const unsigned short* __restrict__ Qb, const unsigned short* __restrict__ Kb,
    const unsigned short* __restrict__ Vt, float* __restrict__ out)
{
    __shared__ alignas(16) unsigned short sQ[64 * 72];
    __shared__ alignas(16) unsigned short sK[64 * 72];
    __shared__ alignas(16) unsigned short sV[64 * 72];      // [d][key]
    __shared__ alignas(16) unsigned short sP[4 * 16 * 72];  // per-wave P tile
    int tid = threadIdx.x;
    int qb = blockIdx.x, bh = blockIdx.y;
    int b = bh >> 3, h = bh & 7;
    int q0 = qb * 64;
    int lane = tid & 63, w = tid >> 6;
    int l16 = lane & 15, lhi = lane >> 4;

    // stage Q tile (64 rows x 64 d)
#pragma unroll
    for (int p = 0; p < 2; ++p) {
        int row = (tid >> 3) + p * 32, ch = tid & 7;
        *(int4*)&sQ[row * 72 + ch * 8] =
            *(const int4*)&Qb[((size_t)bh * SEQ + q0 + row) * HDIM + ch * 8];
    }
    __syncthreads();
    bf16x8 qf0 = *(const bf16x8*)&sQ[(w * 16 + l16) * 72 + 0 + lhi * 8];
    bf16x8 qf1 = *(const bf16x8*)&sQ[(w * 16 + l16) * 72 + 32 + lhi * 8];

    float m_r[4], l_r[4];
    f32x4 o[4];
    f32x4 zero = {0.f, 0.f, 0.f, 0.f};
#pragma unroll
    for (int r = 0; r < 4; ++r) { m_r[r] = -1e30f; l_r[r] = 0.f; }
#pragma unroll
    for (int df = 0; df < 4; ++df) o[df] = zero;

    for (int kt = 0; kt <= qb; ++kt) {
        int k0 = kt * 64;
        __syncthreads();  // previous iter's reads done before overwrite
#pragma unroll
        for (int p = 0; p < 2; ++p) {
            int row = (tid >> 3) + p * 32, ch = tid & 7;
            *(int4*)&sK[row * 72 + ch * 8] =
                *(const int4*)&Kb[((size_t)bh * SEQ + k0 + row) * HDIM + ch * 8];
            *(int4*)&sV[row * 72 + ch * 8] =
                *(const int4*)&Vt[((size_t)bh * HDIM + row) * SEQ + k0 + ch * 8];
        }
        __syncthreads();

        // S = Q K^T  (scale already folded into Q)
        f32x4 sc4[4];
#pragma unroll
        for (int kf = 0; kf < 4; ++kf) {
            bf16x8 kb0 = *(const bf16x8*)&sK[(kf * 16 + l16) * 72 + 0 + lhi * 8];
            bf16x8 kb1 = *(const bf16x8*)&sK[(kf * 16 + l16) * 72 + 32 + lhi * 8];
            f32x4 zacc = zero;
            zacc = mfma16(qf0, kb0, zacc);
            zacc = mfma16(qf1, kb1, zacc);
            sc4[kf] = zacc;
        }
        if (kt == qb) {  // diagonal tile: causal mask k > q
#pragma unroll
            for (int kf = 0; kf < 4; ++kf)
#pragma unroll
                for (int r = 0; r < 4; ++r) {
                    int kg = k0 + kf * 16 + l16;
                    int qg = q0 + w * 16 + lhi * 4 + r;
                    if (kg > qg) sc4[kf][r] = -1e30f;
                }
        }

        // online softmax (row r lives in this lane's 16-lane group)
        float p4[4][4];
        float corr[4];
#pragma unroll
        for (int r = 0; r < 4; ++r) {
            float tm = fmaxf(fmaxf(sc4[0][r], sc4[1][r]), fmaxf(sc4[2][r], sc4[3][r]));
            tm = fmaxf(tm, __shfl_xor(tm, 1));
            tm = fmaxf(tm, __shfl_xor(tm, 2));
            tm = fmaxf(tm, __shfl_xor(tm, 4));
            tm = fmaxf(tm, __shfl_xor(tm, 8));
            float mnew = fmaxf(m_r[r], tm);
            corr[r] = __expf(m_r[r] - mnew);
            float ts = 0.f;
#pragma unroll
            for (int kf = 0; kf < 4; ++kf) {
                p4[kf][r] = __expf(sc4[kf][r] - mnew);
                ts += p4[kf][r];
            }
            ts += __shfl_xor(ts, 1);
            ts += __shfl_xor(ts, 2);
            ts += __shfl_xor(ts, 4);
            ts += __shfl_xor(ts, 8);
            l_r[r] = l_r[r] * corr[r] + ts;
            m_r[r] = mnew;
        }
#pragma unroll
        for (int df = 0; df < 4; ++df)
#pragma unroll
            for (int r = 0; r < 4; ++r) o[df][r] *= corr[r];

        // P -> bf16 -> wave-private LDS, reload in A-fragment layout
#pragma unroll
        for (int kf = 0; kf < 4; ++kf)
#pragma unroll
            for (int r = 0; r < 4; ++r)
                sP[(w * 16 + lhi * 4 + r) * 72 + kf * 16 + l16] = f2b(p4[kf][r]);
        bf16x8 pa0 = *(const bf16x8*)&sP[(w * 16 + l16) * 72 + 0 + lhi * 8];
        bf16x8 pa1 = *(const bf16x8*)&sP[(w * 16 + l16) * 72 + 32 + lhi * 8];

        // O += P V   (V^T in LDS: row d, col key)
#pragma unroll
        for (int df = 0; df < 4; ++df) {
            bf16x8 vb0 = *(const bf16x8*)&sV[(df * 16 + l16) * 72 + 0 + lhi * 8];
            bf16x8 vb1 = *(const bf16x8*)&sV[(df * 16 + l16) * 72 + 32 + lhi * 8];
            o[df] = mfma16(pa0, vb0, o[df]);
            o[df] = mfma16(pa1, vb1, o[df]);
        }
    }

    // epilogue: divide by l, write f32 (B, E, S); 4 r-rows are consecutive s
    float inv[4];
#pragma unroll
    for (int r = 0; r < 4; ++r) inv[r] = 1.0f / l_r[r];
#pragma unroll
    for (int df = 0; df < 4; ++df) {
        float4 ov;
        ov.x = o[df][0] * inv[0];
        ov.y = o[df][1] * inv[1];
        ov.z = o[df][2] * inv[2];
        ov.w = o[df][3] * inv[3];
        int dd = df * 16 + l16;
        size_t addr = ((size_t)b * EMB + h * HDIM + dd) * SEQ + q0 + w * 16 + lhi * 4;
        *(float4*)&out[addr] = ov;
    }
}

// ---------------------------------------------------------------------------
extern "C" void kernel_launch(void* const* d_in, const int* in_sizes, int n_in,
                              void* d_out, int out_size, void* d_ws, size_t ws_size,
                              hipStream_t stream) {
    const float* query = (const float*)d_in[0];
    const float* key_  = (const float*)d_in[1];
    const float* Wq    = (const float*)d_in[2];
    const float* bq    = (const float*)d_in[3];
    const float* Wk    = (const float*)d_in[4];
    const float* bk    = (const float*)d_in[5];
    const float* Wv    = (const float*)d_in[6];
    const float* bv    = (const float*)d_in[7];
    float* out = (float*)d_out;

    char* ws = (char*)d_ws;
    // workspace layout (32 MiB total)
    unsigned short* Qb = (unsigned short*)(ws);                    // 8 MiB (B,H,S,D)
    unsigned short* Kb = (unsigned short*)(ws + 8388608);          // 8 MiB (B,H,S,D)
    unsigned short* Vt = (unsigned short*)(ws + 16777216);         // 8 MiB (B,H,D,S)
    unsigned short* Xq = (unsigned short*)(ws + 25165824);         // 4 MiB (B,S,C)
    unsigned short* Xk = (unsigned short*)(ws + 29360128);         // 4 MiB (B,S,C)

    transpose_cvt<<<dim3(SEQ / 64, CDIM / 64, 2 * BATCH), 256, 0, stream>>>(query, key_, Xq, Xk);
    proj_kernel<<<dim3(EMB / 64, SEQ / 128, 3 * BATCH), 256, 0, stream>>>(
        Xq, Xk, Wq, bq, Wk, bk, Wv, bv, Qb, Kb, Vt);
    attn_kernel<<<dim3(SEQ / 64, BATCH * NHEAD), 256, 0, stream>>>(Qb, Kb, Vt, out);
}

// Round 2
// 139.852 us; speedup vs baseline: 1.3195x; 1.3195x over previous
//
#include <hip/hip_runtime.h>
#include <hip/hip_bf16.h>

// Problem constants
#define BATCH 8
#define CDIM 256     // QDIM == KDIM
#define SEQ 1024     // 32*32
#define EMB 512
#define NHEAD 8
#define HDIM 64

typedef __bf16 bf16x8 __attribute__((ext_vector_type(8)));
typedef float f32x4 __attribute__((ext_vector_type(4)));
typedef float f32x16 __attribute__((ext_vector_type(16)));

static __device__ __forceinline__ unsigned short f2b(float f) {
    __hip_bfloat16 h = __float2bfloat16(f);
    return __builtin_bit_cast(unsigned short, h);
}

static __device__ __forceinline__ f32x4 mfma16(bf16x8 a, bf16x8 b, f32x4 c) {
    return __builtin_amdgcn_mfma_f32_16x16x32_bf16(a, b, c, 0, 0, 0);
}
static __device__ __forceinline__ f32x16 mfma32(bf16x8 a, bf16x8 b, f32x16 c) {
    return __builtin_amdgcn_mfma_f32_32x32x16_bf16(a, b, c, 0, 0, 0);
}

// ---------------------------------------------------------------------------
// Kernel 0: W f32 (3 x 512 x 256) -> Wc bf16 (1536 x 256), once per launch.
// grid (64, 1, 3), block 256; each thread converts 8 elements.
// ---------------------------------------------------------------------------
__global__ __launch_bounds__(256) void prep_w(
    const float* __restrict__ Wq, const float* __restrict__ Wk,
    const float* __restrict__ Wv, unsigned short* __restrict__ Wc)
{
    int pz = blockIdx.z;
    const float* W = (pz == 0) ? Wq : (pz == 1 ? Wk : Wv);
    int idx = (blockIdx.x * 256 + threadIdx.x) * 8;  // 0 .. 131064
    float4 v0 = *(const float4*)&W[idx];
    float4 v1 = *(const float4*)&W[idx + 4];
    int4 pk;
    pk.x = (int)((unsigned)f2b(v0.x) | ((unsigned)f2b(v0.y) << 16));
    pk.y = (int)((unsigned)f2b(v0.z) | ((unsigned)f2b(v0.w) << 16));
    pk.z = (int)((unsigned)f2b(v1.x) | ((unsigned)f2b(v1.y) << 16));
    pk.w = (int)((unsigned)f2b(v1.z) | ((unsigned)f2b(v1.w) << 16));
    *(int4*)&Wc[(size_t)pz * (EMB * CDIM) + idx] = pk;
}

// ---------------------------------------------------------------------------
// Kernel 1: (B, C, S) f32 -> (B, S, C) bf16 transpose+convert, 64x64 LDS tiles
// grid (S/64=16, C/64=4, 2*B=16), block 256
// ---------------------------------------------------------------------------
__global__ __launch_bounds__(256) void transpose_cvt(
    const float* __restrict__ query, const float* __restrict__ key_,
    unsigned short* __restrict__ Xq, unsigned short* __restrict__ Xk)
{
    __shared__ alignas(16) unsigned short sT[64 * 66];
    int tid = threadIdx.x;
    int s0 = blockIdx.x * 64, c0 = blockIdx.y * 64;
    int z = blockIdx.z;
    int which = z >> 3, b = z & 7;
    const float* src = which ? key_ : query;
    unsigned short* dst = which ? Xk : Xq;

#pragma unroll
    for (int p = 0; p < 4; ++p) {
        int c = (tid >> 4) + p * 16;
        int sch = tid & 15;
        float4 v = *(const float4*)&src[((size_t)b * CDIM + c0 + c) * SEQ + s0 + sch * 4];
        sT[c * 66 + sch * 4 + 0] = f2b(v.x);
        sT[c * 66 + sch * 4 + 1] = f2b(v.y);
        sT[c * 66 + sch * 4 + 2] = f2b(v.z);
        sT[c * 66 + sch * 4 + 3] = f2b(v.w);
    }
    __syncthreads();
#pragma unroll
    for (int p = 0; p < 4; ++p) {
        int s = (tid >> 4) + p * 16;
        int cch = tid & 15;
        unsigned short e0 = sT[(cch * 4 + 0) * 66 + s];
        unsigned short e1 = sT[(cch * 4 + 1) * 66 + s];
        unsigned short e2 = sT[(cch * 4 + 2) * 66 + s];
        unsigned short e3 = sT[(cch * 4 + 3) * 66 + s];
        uint2 pk;
        pk.x = (unsigned)e0 | ((unsigned)e1 << 16);
        pk.y = (unsigned)e2 | ((unsigned)e3 << 16);
        *(uint2*)&dst[((size_t)b * SEQ + s0 + s) * CDIM + c0 + cch * 4] = pk;
    }
}

// ---------------------------------------------------------------------------
// Kernel 2: fused projection GEMM over M = B*S = 8192, N = 1536 (Wq|Wk|Wv).
// BM=128 BN=128 BK=64, 4 waves (2x2), wave tile 64x64, 16x16x32 MFMA.
// proj==2 (V) swaps MFMA operands so the (B,H,D,S) store is s-contiguous.
// Q epilogue folds 0.125*log2(e) (attention scale, exp2 domain).
// grid (N/128=12, M/128=64), block 256
// ---------------------------------------------------------------------------
__global__ __launch_bounds__(256) void proj_kernel(
    const unsigned short* __restrict__ Xq, const unsigned short* __restrict__ Xk,
    const unsigned short* __restrict__ Wc,
    const float* __restrict__ bq, const float* __restrict__ bk,
    const float* __restrict__ bv,
    unsigned short* __restrict__ Qb, unsigned short* __restrict__ Kb,
    unsigned short* __restrict__ Vt)
{
    __shared__ alignas(16) unsigned short sA[128 * 72];  // X rows (s)
    __shared__ alignas(16) unsigned short sB[128 * 72];  // W rows (e)
    int tid = threadIdx.x;
    int n0 = blockIdx.x * 128;  // 0..1535 (proj region = n0>>9)
    int m0 = blockIdx.y * 128;  // 0..8191 (never straddles a batch)
    int proj = n0 >> 9;
    const unsigned short* X = (proj == 0) ? Xq : Xk;
    const float* bias = (proj == 0) ? bq : (proj == 1 ? bk : bv);

    int lane = tid & 63, w = tid >> 6;
    int l16 = lane & 15, lhi = lane >> 4;
    int wr = w >> 1, wc = w & 1;

    f32x4 zero = {0.f, 0.f, 0.f, 0.f};
    f32x4 acc[4][4];
#pragma unroll
    for (int i = 0; i < 4; ++i)
#pragma unroll
        for (int j = 0; j < 4; ++j) acc[i][j] = zero;

    for (int kt = 0; kt < 4; ++kt) {
        int c0 = kt * 64;
        if (kt) __syncthreads();
#pragma unroll
        for (int p = 0; p < 4; ++p) {
            int row = (tid >> 3) + p * 32, ch = tid & 7;
            *(int4*)&sA[row * 72 + ch * 8] =
                *(const int4*)&X[(size_t)(m0 + row) * CDIM + c0 + ch * 8];
            *(int4*)&sB[row * 72 + ch * 8] =
                *(const int4*)&Wc[(size_t)(n0 + row) * CDIM + c0 + ch * 8];
        }
        __syncthreads();
        const unsigned short* tA = (proj == 2) ? &sB[0] : &sA[0];
        const unsigned short* tB = (proj == 2) ? &sA[0] : &sB[0];
#pragma unroll
        for (int kk = 0; kk < 2; ++kk) {
            bf16x8 af[4], bfr[4];
#pragma unroll
            for (int i = 0; i < 4; ++i)
                af[i] = *(const bf16x8*)&tA[(wr * 64 + i * 16 + l16) * 72 + kk * 32 + lhi * 8];
#pragma unroll
            for (int j = 0; j < 4; ++j)
                bfr[j] = *(const bf16x8*)&tB[(wc * 64 + j * 16 + l16) * 72 + kk * 32 + lhi * 8];
#pragma unroll
            for (int i = 0; i < 4; ++i)
#pragma unroll
                for (int j = 0; j < 4; ++j)
                    acc[i][j] = mfma16(af[i], bfr[j], acc[i][j]);
        }
    }

    if (proj != 2) {
        unsigned short* dst = proj ? Kb : Qb;
        float scale = proj ? 1.0f : (0.125f * 1.44269504f);  // Q: /sqrt(64) * log2e
#pragma unroll
        for (int i = 0; i < 4; ++i) {
#pragma unroll
            for (int j = 0; j < 4; ++j) {
                int e = (n0 & 511) + wc * 64 + j * 16 + l16;
                float bval = bias[e];
                int hh = e >> 6, dd = e & 63;
#pragma unroll
                for (int r = 0; r < 4; ++r) {
                    int mg = m0 + wr * 64 + i * 16 + lhi * 4 + r;
                    int bb = mg >> 10, s = mg & 1023;
                    dst[(((size_t)bb * NHEAD + hh) * SEQ + s) * HDIM + dd] =
                        f2b((acc[i][j][r] + bval) * scale);
                }
            }
        }
    } else {
        // operands were swapped: acc row index i -> e-dim, col index j -> s-dim
#pragma unroll
        for (int i = 0; i < 4; ++i) {
#pragma unroll
            for (int r = 0; r < 4; ++r) {
                int e = (n0 & 511) + wr * 64 + i * 16 + lhi * 4 + r;
                float bval = bias[e];
                int hh = e >> 6, dd = e & 63;
#pragma unroll
                for (int j = 0; j < 4; ++j) {
                    int mg = m0 + wc * 64 + j * 16 + l16;
                    int bb = mg >> 10, s = mg & 1023;
                    Vt[(((size_t)bb * NHEAD + hh) * HDIM + dd) * SEQ + s] =
                        f2b(acc[i][j][r] + bval);
                }
            }
        }
    }
}

// ---------------------------------------------------------------------------
// Kernel 3: causal flash attention. 1 wave per block, 32 q-rows per wave.
// Swapped QK^T (mfma(K,Q) -> S^T: lane owns one q-row => softmax is a register
// chain + one shfl_xor(32)). P->bf16 via v_cvt_pk_bf16_f32 + permlane32_swap
// (no LDS at all, no barriers). K/V read as fragments from global (L2-hot).
// exp2 domain (log2e folded into Q), defer-max THR=8.
// grid (B*H=64, S/32=32): all q-blocks of a head land on one XCD (64%8==0);
// y=0 gets the longest (qt=31) block for load balance.
// ---------------------------------------------------------------------------
__global__ __launch_bounds__(64, 3) void attn_kernel(
    const unsigned short* __restrict__ Qb, const unsigned short* __restrict__ Kb,
    const unsigned short* __restrict__ Vt, float* __restrict__ out)
{
    int lane = threadIdx.x;
    int l32 = lane & 31, hi = lane >> 5;
    int bh = blockIdx.x;
    int qt = (int)(gridDim.y - 1 - blockIdx.y);
    int b = bh >> 3, h = bh & 7;
    int q0 = qt * 32;

    const unsigned short* Qhead = Qb + (size_t)bh * SEQ * HDIM;
    const unsigned short* Khead = Kb + (size_t)bh * SEQ * HDIM;
    const unsigned short* Vhead = Vt + (size_t)bh * HDIM * SEQ;

    // resident Q fragments (B-operand): lane l32 = q row, hi*8 = d offset
    bf16x8 qf[4];
#pragma unroll
    for (int dblk = 0; dblk < 4; ++dblk)
        qf[dblk] = *(const bf16x8*)&Qhead[(size_t)(q0 + l32) * HDIM + dblk * 16 + hi * 8];

    f32x16 o0, o1;
#pragma unroll
    for (int r = 0; r < 16; ++r) { o0[r] = 0.f; o1[r] = 0.f; }
    float m = -1e30f, l = 0.f;

    int nt = qt + 1;
    for (int kt = 0; kt < nt; ++kt) {
        int k0 = kt * 32;
        // K fragments (A-operand): lane l32 = k row
        bf16x8 ka[4];
#pragma unroll
        for (int dblk = 0; dblk < 4; ++dblk)
            ka[dblk] = *(const bf16x8*)&Khead[(size_t)(k0 + l32) * HDIM + dblk * 16 + hi * 8];
        f32x16 st;
#pragma unroll
        for (int r = 0; r < 16; ++r) st[r] = 0.f;
#pragma unroll
        for (int dblk = 0; dblk < 4; ++dblk)
            st = mfma32(ka[dblk], qf[dblk], st);

        // V fragments (A-operand for PV): issue early, consumed after softmax
        bf16x8 va[2][2];
#pragma unroll
        for (int t = 0; t < 2; ++t)
#pragma unroll
            for (int ks = 0; ks < 2; ++ks)
                va[t][ks] = *(const bf16x8*)
                    &Vhead[(size_t)(t * 32 + l32) * SEQ + k0 + ks * 16 + hi * 8];

        if (kt == qt) {  // diagonal tile: mask k > q (k0 == q0)
#pragma unroll
            for (int r = 0; r < 16; ++r) {
                int kk = (r & 3) + 8 * (r >> 2) + 4 * hi;
                if (kk > l32) st[r] = -1e38f;
            }
        }

        // row max: registers + one cross-half shuffle (lane owns q = l32)
        float tmax = st[0];
#pragma unroll
        for (int r = 1; r < 16; ++r) tmax = fmaxf(tmax, st[r]);
        tmax = fmaxf(tmax, __shfl_xor(tmax, 32));
        if (!__all(tmax <= m + 8.0f)) {  // defer-max (T13), exp2 domain
            float mnew = fmaxf(m, tmax);
            float corr = __builtin_amdgcn_exp2f(m - mnew);
#pragma unroll
            for (int r = 0; r < 16; ++r) { o0[r] *= corr; o1[r] *= corr; }
            l *= corr;
            m = mnew;
        }
        float p[16];
        float ts = 0.f;
#pragma unroll
        for (int r = 0; r < 16; ++r) {
            p[r] = __builtin_amdgcn_exp2f(st[r] - m);
            ts += p[r];
        }
        ts += __shfl_xor(ts, 32);
        l += ts;

        // pack P to bf16 pairs; permlane32_swap redistributes k across halves.
        // reg r holds k = (r&3) + 8*(r>>2) + 4*hi; frag word j needs k = hi*8+2j.
        unsigned u[8];
#pragma unroll
        for (int i = 0; i < 8; ++i) {
            unsigned r_;
            asm("v_cvt_pk_bf16_f32 %0, %1, %2" : "=v"(r_) : "v"(p[2 * i]), "v"(p[2 * i + 1]));
            u[i] = r_;
        }
        asm("v_permlane32_swap_b32 %0, %1" : "+v"(u[0]), "+v"(u[2]));
        asm("v_permlane32_swap_b32 %0, %1" : "+v"(u[1]), "+v"(u[3]));
        asm("v_permlane32_swap_b32 %0, %1" : "+v"(u[4]), "+v"(u[6]));
        asm("v_permlane32_swap_b32 %0, %1" : "+v"(u[5]), "+v"(u[7]));
        uint4 pw0 = {u[0], u[1], u[2], u[3]};
        uint4 pw1 = {u[4], u[5], u[6], u[7]};
        bf16x8 pb0 = __builtin_bit_cast(bf16x8, pw0);
        bf16x8 pb1 = __builtin_bit_cast(bf16x8, pw1);

        // O^T += V^T . P^T  (m = d, n = q)
        o0 = mfma32(va[0][0], pb0, o0);
        o1 = mfma32(va[1][0], pb0, o1);
        o0 = mfma32(va[0][1], pb1, o0);
        o1 = mfma32(va[1][1], pb1, o1);
    }

    float inv = 1.0f / l;
    size_t base = ((size_t)b * EMB + h * HDIM) * SEQ + q0 + l32;
#pragma unroll
    for (int r = 0; r < 16; ++r) {
        int d0 = (r & 3) + 8 * (r >> 2) + 4 * hi;
        out[base + (size_t)d0 * SEQ] = o0[r] * inv;
        out[base + (size_t)(d0 + 32) * SEQ] = o1[r] * inv;
    }
}

// ---------------------------------------------------------------------------
extern "C" void kernel_launch(void* const* d_in, const int* in_sizes, int n_in,
                              void* d_out, int out_size, void* d_ws, size_t ws_size,
                              hipStream_t stream) {
    const float* query = (const float*)d_in[0];
    const float* key_  = (const float*)d_in[1];
    const float* Wq    = (const float*)d_in[2];
    const float* bq    = (const float*)d_in[3];
    const float* Wk    = (const float*)d_in[4];
    const float* bk    = (const float*)d_in[5];
    const float* Wv    = (const float*)d_in[6];
    const float* bv    = (const float*)d_in[7];
    float* out = (float*)d_out;

    char* ws = (char*)d_ws;
    // workspace layout (32 MiB total)
    unsigned short* Qb = (unsigned short*)(ws);                    // 8 MiB (B,H,S,D)
    unsigned short* Kb = (unsigned short*)(ws + 8388608);          // 8 MiB (B,H,S,D)
    unsigned short* Vt = (unsigned short*)(ws + 16777216);         // 8 MiB (B,H,D,S)
    unsigned short* Xq = (unsigned short*)(ws + 25165824);         // 4 MiB (B,S,C)
    unsigned short* Xk = (unsigned short*)(ws + 29360128);         // 4 MiB (B,S,C)
    // Wc (1536x256 bf16, 768 KiB) lives in the tail of d_out; the attention
    // kernel overwrites all of d_out afterwards (stream-ordered), so it is
    // free scratch during prep/proj.
    unsigned short* Wc = (unsigned short*)((char*)d_out + 16777216 - 1048576);

    prep_w<<<dim3(64, 1, 3), 256, 0, stream>>>(Wq, Wk, Wv, Wc);
    transpose_cvt<<<dim3(SEQ / 64, CDIM / 64, 2 * BATCH), 256, 0, stream>>>(query, key_, Xq, Xk);
    proj_kernel<<<dim3(12, 64), 256, 0, stream>>>(Xq, Xk, Wc, bq, bk, bv, Qb, Kb, Vt);
    attn_kernel<<<dim3(BATCH * NHEAD, SEQ / 32), 64, 0, stream>>>(Qb, Kb, Vt, out);
}